// Round 8
// baseline (237.876 us; speedup 1.0000x reference)
//
#include <hip/hip_runtime.h>

// GCN 2-layer: radix-partition CSR build + bf16 MFMA GEMMs + wave-per-node gather.
//   h0s = bf16(dinv*(X@W1)); h = bf16(relu(dinv*(gather+self)+b1))
//   h1s = bf16(dinv*(h@W2)); out = fp32(dinv*(gather+self)+b2)

#define DI 256
#define DH 128
#define DO 64
#define NBC 98          // coarse buckets: ceil(50000/512)
#define EPB 8192        // edges per partition block
#define P4CAP 12288     // per-bucket sort capacity (avg 8163, +45 sigma)

typedef unsigned short ushort;
typedef unsigned int uint;
using bf16x8 = __attribute__((ext_vector_type(8))) short;
using f32x4  = __attribute__((ext_vector_type(4))) float;

__device__ __forceinline__ ushort f2b(float f) {
    union { float f; uint u; } v; v.f = f;
    uint r = (v.u + 0x7fffu + ((v.u >> 16) & 1u)) >> 16;   // RNE
    return (ushort)r;
}
__device__ __forceinline__ float blo(uint v) { return __uint_as_float(v << 16); }
__device__ __forceinline__ float bhi(uint v) { return __uint_as_float(v & 0xffff0000u); }

// ---------------- CSR build: radix partition ----------------
__global__ __launch_bounds__(256) void hist_k(const int* __restrict__ dst,
                                              int* __restrict__ hist, int E) {
    __shared__ int lh[NBC];
    const int blk = blockIdx.x;
    for (int i = threadIdx.x; i < NBC; i += 256) lh[i] = 0;
    __syncthreads();
    const int base = blk * EPB, end = min(base + EPB, E);
    for (int e = base + threadIdx.x; e < end; e += 256)
        atomicAdd(&lh[dst[e] >> 9], 1);
    __syncthreads();
    for (int i = threadIdx.x; i < NBC; i += 256) hist[blk * NBC + i] = lh[i];
}

__global__ void scan_mat(int* __restrict__ hist, int* __restrict__ boff,
                         int* __restrict__ off, int nbp, int n, int E) {
    __shared__ int mat[NBC * NBC];
    __shared__ int tot[NBC], bo[NBC];
    const int tid = threadIdx.x;
    const int tote = nbp * NBC;
    for (int i = tid; i < tote; i += 256) mat[i] = hist[i];
    __syncthreads();
    if (tid < NBC) {
        int run = 0;
        for (int b = 0; b < nbp; ++b) {
            int v = mat[b * NBC + tid];
            mat[b * NBC + tid] = run;
            run += v;
        }
        tot[tid] = run;
    }
    __syncthreads();
    if (tid == 0) {
        int r = 0;
        for (int c = 0; c < NBC; ++c) { bo[c] = r; r += tot[c]; }
        boff[NBC] = r;
        off[n] = E;
    }
    __syncthreads();
    if (tid < NBC) boff[tid] = bo[tid];
    for (int i = tid; i < tote; i += 256) hist[i] = mat[i] + bo[i % NBC];
}

__global__ __launch_bounds__(256) void part_k(const int* __restrict__ src,
                                              const int* __restrict__ dst,
                                              const int* __restrict__ hist,
                                              uint* __restrict__ pairs, int E) {
    __shared__ int cur[NBC];
    const int blk = blockIdx.x;
    for (int i = threadIdx.x; i < NBC; i += 256) cur[i] = hist[blk * NBC + i];
    __syncthreads();
    const int base = blk * EPB, end = min(base + EPB, E);
    for (int e = base + threadIdx.x; e < end; e += 256) {
        int d = dst[e], s = src[e];
        int slot = atomicAdd(&cur[d >> 9], 1);
        pairs[slot] = ((uint)s << 9) | (uint)(d & 511);
    }
}

__global__ __launch_bounds__(256) void bucket_k(const uint* __restrict__ pairs,
                                                const int* __restrict__ boff,
                                                int* __restrict__ off,
                                                float* __restrict__ dinv,
                                                int* __restrict__ csr, int n) {
    __shared__ int lh[512], lcur[512], tsum[256];
    __shared__ int sorted[P4CAP];
    const int tid = threadIdx.x;
    const int cb = blockIdx.x;
    const int b0 = boff[cb], b1 = boff[cb + 1];
    const int cnt = b1 - b0;
    lh[tid] = 0; lh[tid + 256] = 0;
    __syncthreads();
    for (int i = tid; i < cnt; i += 256) atomicAdd(&lh[pairs[b0 + i] & 511], 1);
    __syncthreads();
    const int s0 = lh[2 * tid], s1 = lh[2 * tid + 1];
    const int s = s0 + s1;
    tsum[tid] = s;
    __syncthreads();
    for (int o = 1; o < 256; o <<= 1) {
        int t = (tid >= o) ? tsum[tid - o] : 0;
        __syncthreads();
        tsum[tid] += t;
        __syncthreads();
    }
    const int ex = tsum[tid] - s;
    lcur[2 * tid] = ex; lcur[2 * tid + 1] = ex + s0;
    {
        int node = cb * 512 + 2 * tid;
        if (node < n)     { off[node]     = b0 + ex;      dinv[node]     = rsqrtf((float)s0 + 1.f); }
        if (node + 1 < n) { off[node + 1] = b0 + ex + s0; dinv[node + 1] = rsqrtf((float)s1 + 1.f); }
    }
    __syncthreads();
    for (int i = tid; i < cnt; i += 256) {
        uint v = pairs[b0 + i];
        int slot = atomicAdd(&lcur[v & 511], 1);
        if (slot < P4CAP) sorted[slot] = (int)(v >> 9);
    }
    __syncthreads();
    const int cs = min(cnt, P4CAP);
    for (int i = tid; i < cs; i += 256) csr[b0 + i] = sorted[i];
}

// both weights in one launch: W1t[m][k], W2t[m][k]
__global__ void wt_cvt2(const float* __restrict__ W1, ushort* __restrict__ W1t,
                        const float* __restrict__ W2, ushort* __restrict__ W2t) {
    int idx = blockIdx.x * 256 + threadIdx.x;
    if (idx < DI * DH) {
        int m = idx / DI, k = idx % DI;
        W1t[idx] = f2b(W1[(long)k * DH + m]);
    }
    if (idx < DH * DO) {
        int m = idx / DH, k = idx % DH;
        W2t[idx] = f2b(W2[(long)k * DO + m]);
    }
}

// ---------------- MFMA GEMM ----------------
// Y[n,M](bf16) = dinv[row] * (X[n,K] @ W[K,M]); Wt is bf16 [M][K].
// BM=64/block, 4 waves; staging: 4 consecutive lanes cover 128B of one row.
template<int K, int M, bool INF32>
__global__ __launch_bounds__(256) void mfma_gemm(const void* __restrict__ Xv,
                                                 const ushort* __restrict__ Wt,
                                                 const float* __restrict__ dinv,
                                                 ushort* __restrict__ Y, int n) {
    constexpr int ROWB = K * 2;
    constexpr int CT = M / 64;
    __shared__ ushort Xs[64 * K];
    const int t = threadIdx.x;
    const int r0 = blockIdx.x * 64;

    {
        const int row = t >> 2, q = t & 3;
        const int gr = r0 + row;
        if (INF32) {
            const float* Xr = (const float*)Xv + (long)gr * K;
#pragma unroll
            for (int j = 0; j < K / 32; ++j) {
                float4 a = make_float4(0.f, 0.f, 0.f, 0.f), b = a;
                if (gr < n) {
                    a = *(const float4*)&Xr[q * 8 + j * 32];
                    b = *(const float4*)&Xr[q * 8 + j * 32 + 4];
                }
                ushort u[8] = {f2b(a.x), f2b(a.y), f2b(a.z), f2b(a.w),
                               f2b(b.x), f2b(b.y), f2b(b.z), f2b(b.w)};
                int byte = row * ROWB + q * 16 + j * 64;
                byte ^= (row & 7) << 4;
                *(uint4*)((char*)Xs + byte) = *(const uint4*)u;
            }
        } else {
            const ushort* Xr = (const ushort*)Xv + (long)gr * K;
#pragma unroll
            for (int j = 0; j < K / 32; ++j) {
                uint4 v = make_uint4(0u, 0u, 0u, 0u);
                if (gr < n) v = *(const uint4*)&Xr[q * 8 + j * 32];
                int byte = row * ROWB + q * 16 + j * 64;
                byte ^= (row & 7) << 4;
                *(uint4*)((char*)Xs + byte) = v;
            }
        }
    }
    __syncthreads();

    const int w  = t >> 6;
    const int l  = t & 63;
    const int lr = l & 15;
    const int lg = l >> 4;
    f32x4 acc[4][CT] = {};

#pragma unroll
    for (int ks = 0; ks < K / 32; ++ks) {
        bf16x8 bfr[CT];
#pragma unroll
        for (int ct = 0; ct < CT; ++ct) {
            int col = w * (M / 4) + ct * 16 + lr;
            bfr[ct] = *(const bf16x8*)&Wt[(long)col * K + ks * 32 + lg * 8];
        }
        bf16x8 afr[4];
#pragma unroll
        for (int rt = 0; rt < 4; ++rt) {
            int row = rt * 16 + lr;
            int byte = row * ROWB + ks * 64 + lg * 16;
            byte ^= (row & 7) << 4;
            afr[rt] = *(const bf16x8*)((const char*)Xs + byte);
        }
#pragma unroll
        for (int rt = 0; rt < 4; ++rt)
#pragma unroll
            for (int ct = 0; ct < CT; ++ct)
                acc[rt][ct] = __builtin_amdgcn_mfma_f32_16x16x32_bf16(
                    afr[rt], bfr[ct], acc[rt][ct], 0, 0, 0);
    }

#pragma unroll
    for (int rt = 0; rt < 4; ++rt)
#pragma unroll
        for (int i = 0; i < 4; ++i) {
            int gr2 = r0 + rt * 16 + lg * 4 + i;
            if (gr2 < n) {
                float dv = dinv[gr2];
#pragma unroll
                for (int ct = 0; ct < CT; ++ct) {
                    int col = w * (M / 4) + ct * 16 + lr;
                    Y[(long)gr2 * M + col] = f2b(dv * acc[rt][ct][i]);
                }
            }
        }
}

// ---------------- gather: one wave per node ----------------
// 64 lanes = GR groups x LPG lanes; group g does edges k0+g, k0+g+GR, ...
// cross-group shfl_xor reduce; group 0 stores.
template<int M, bool RELU, bool OUTF32>
__global__ __launch_bounds__(256) void gather_wave(const int* __restrict__ off,
                                                   const int* __restrict__ csr,
                                                   const ushort* __restrict__ Hs,
                                                   const float* __restrict__ dinv,
                                                   const float* __restrict__ b,
                                                   void* __restrict__ Yv, int n) {
    constexpr int LPG = M / 8;         // lanes per edge-group (16B each)
    constexpr int GR  = 64 / LPG;      // edge groups per wave (4 or 8)
    const int wv = threadIdx.x >> 6;
    const int ln = threadIdx.x & 63;
    const int grp = ln / LPG;
    const int j   = ln % LPG;
    const int i = blockIdx.x * 4 + wv;
    if (i >= n) return;
    const uint4* H4 = (const uint4*)Hs;
    float acc[8] = {0.f, 0.f, 0.f, 0.f, 0.f, 0.f, 0.f, 0.f};
    const int k0 = off[i], ke = off[i + 1];
    for (int k = k0 + grp; k < ke; k += GR) {
        uint4 a = H4[(long)csr[k] * LPG + j];
        acc[0] += blo(a.x); acc[1] += bhi(a.x);
        acc[2] += blo(a.y); acc[3] += bhi(a.y);
        acc[4] += blo(a.z); acc[5] += bhi(a.z);
        acc[6] += blo(a.w); acc[7] += bhi(a.w);
    }
    if (grp == 0) {                    // self loop
        uint4 a = H4[(long)i * LPG + j];
        acc[0] += blo(a.x); acc[1] += bhi(a.x);
        acc[2] += blo(a.y); acc[3] += bhi(a.y);
        acc[4] += blo(a.z); acc[5] += bhi(a.z);
        acc[6] += blo(a.w); acc[7] += bhi(a.w);
    }
#pragma unroll
    for (int o = LPG; o < 64; o <<= 1)
#pragma unroll
        for (int m = 0; m < 8; ++m) acc[m] += __shfl_xor(acc[m], o, 64);
    if (grp == 0) {
        float di = dinv[i];
        float4 b0 = ((const float4*)b)[j * 2];
        float4 b1 = ((const float4*)b)[j * 2 + 1];
        float r[8];
        r[0] = di * acc[0] + b0.x; r[1] = di * acc[1] + b0.y;
        r[2] = di * acc[2] + b0.z; r[3] = di * acc[3] + b0.w;
        r[4] = di * acc[4] + b1.x; r[5] = di * acc[5] + b1.y;
        r[6] = di * acc[6] + b1.z; r[7] = di * acc[7] + b1.w;
        if (RELU) {
#pragma unroll
            for (int m = 0; m < 8; ++m) r[m] = fmaxf(r[m], 0.f);
        }
        if (OUTF32) {
            float* Y = (float*)Yv;
            *(float4*)&Y[(long)i * M + j * 8]     = make_float4(r[0], r[1], r[2], r[3]);
            *(float4*)&Y[(long)i * M + j * 8 + 4] = make_float4(r[4], r[5], r[6], r[7]);
        } else {
            ushort* Y = (ushort*)Yv;
            uint4 o;
            o.x = (uint)f2b(r[0]) | ((uint)f2b(r[1]) << 16);
            o.y = (uint)f2b(r[2]) | ((uint)f2b(r[3]) << 16);
            o.z = (uint)f2b(r[4]) | ((uint)f2b(r[5]) << 16);
            o.w = (uint)f2b(r[6]) | ((uint)f2b(r[7]) << 16);
            *(uint4*)&Y[(long)i * M + j * 8] = o;
        }
    }
}

extern "C" void kernel_launch(void* const* d_in, const int* in_sizes, int n_in,
                              void* d_out, int out_size, void* d_ws, size_t ws_size,
                              hipStream_t stream) {
    const float* x  = (const float*)d_in[0];
    const int*   ei = (const int*)d_in[1];
    const float* W1 = (const float*)d_in[2];
    const float* b1 = (const float*)d_in[3];
    const float* W2 = (const float*)d_in[4];
    const float* b2 = (const float*)d_in[5];
    float* out = (float*)d_out;

    const int n = in_sizes[0] / DI;   // 50000
    const int E = in_sizes[1] / 2;    // 800000
    const int* src = ei;
    const int* dst = ei + E;
    const int np  = ((n + 255) / 256) * 256;
    const int nbp = (E + EPB - 1) / EPB;   // 98
    const int nbc = (n + 511) >> 9;        // 98

    int*    hist  = (int*)d_ws;
    int*    boff  = hist + NBC * NBC;
    int*    off   = boff + 128;
    float*  dinv  = (float*)(off + np + 256);
    int*    csr   = (int*)(dinv + np);
    uint*   pairs = (uint*)(csr + E);
    ushort* w1t   = (ushort*)(pairs + E);
    ushort* w2t   = w1t + DH * DI;
    ushort* h0s   = w2t + DO * DH;
    ushort* h     = h0s + (size_t)n * DH;
    ushort* h1s   = h0s;              // reuse after gather1

    hist_k<<<nbp, 256, 0, stream>>>(dst, hist, E);
    scan_mat<<<1, 256, 0, stream>>>(hist, boff, off, nbp, n, E);
    part_k<<<nbp, 256, 0, stream>>>(src, dst, hist, pairs, E);
    bucket_k<<<nbc, 256, 0, stream>>>(pairs, boff, off, dinv, csr, n);
    wt_cvt2<<<(DI * DH + 255) / 256, 256, 0, stream>>>(W1, w1t, W2, w2t);

    const int gblk = (n + 63) / 64;
    mfma_gemm<DI, DH, true><<<gblk, 256, 0, stream>>>(x, w1t, dinv, h0s, n);
    gather_wave<DH, true, false><<<(n + 3) / 4, 256, 0, stream>>>(off, csr, h0s, dinv, b1, h, n);
    mfma_gemm<DH, DO, false><<<gblk, 256, 0, stream>>>(h, w2t, dinv, h1s, n);
    gather_wave<DO, false, true><<<(n + 3) / 4, 256, 0, stream>>>(off, csr, h1s, dinv, b2, out, n);
}

// Round 9
// 232.904 us; speedup vs baseline: 1.0213x; 1.0213x over previous
//
#include <hip/hip_runtime.h>

// GCN 2-layer: radix CSR build + bf16 MFMA + fused gather+GEMM layer boundary.
//   h0s = bf16(dinv*(X@W1))                       (mfma_gemm)
//   h1s = bf16(dinv*( relu(dinv*(gather h0s)+b1) @ W2 ))   (fused, h LDS-only)
//   out = fp32(dinv*(gather h1s + self) + b2)     (gather_wave)

#define DI 256
#define DH 128
#define DO 64
#define NBC 98
#define EPB 8192
#define P4CAP 12288

typedef unsigned short ushort;
typedef unsigned int uint;
using bf16x8 = __attribute__((ext_vector_type(8))) short;
using f32x4  = __attribute__((ext_vector_type(4))) float;

__device__ __forceinline__ ushort f2b(float f) {
    union { float f; uint u; } v; v.f = f;
    uint r = (v.u + 0x7fffu + ((v.u >> 16) & 1u)) >> 16;   // RNE
    return (ushort)r;
}
__device__ __forceinline__ float blo(uint v) { return __uint_as_float(v << 16); }
__device__ __forceinline__ float bhi(uint v) { return __uint_as_float(v & 0xffff0000u); }

// ---------------- CSR build: radix partition ----------------
__global__ __launch_bounds__(256) void hist_k(const int* __restrict__ dst,
                                              int* __restrict__ hist, int E) {
    __shared__ int lh[NBC];
    const int blk = blockIdx.x;
    for (int i = threadIdx.x; i < NBC; i += 256) lh[i] = 0;
    __syncthreads();
    const int base = blk * EPB, end = min(base + EPB, E);
    for (int e = base + threadIdx.x; e < end; e += 256)
        atomicAdd(&lh[dst[e] >> 9], 1);
    __syncthreads();
    for (int i = threadIdx.x; i < NBC; i += 256) hist[blk * NBC + i] = lh[i];
}

__global__ void scan_mat(int* __restrict__ hist, int* __restrict__ boff,
                         int* __restrict__ off, int nbp, int n, int E) {
    __shared__ int mat[NBC * NBC];
    __shared__ int tot[NBC], bo[NBC];
    const int tid = threadIdx.x;
    const int tote = nbp * NBC;
    for (int i = tid; i < tote; i += 256) mat[i] = hist[i];
    __syncthreads();
    if (tid < NBC) {
        int run = 0;
        for (int b = 0; b < nbp; ++b) {
            int v = mat[b * NBC + tid];
            mat[b * NBC + tid] = run;
            run += v;
        }
        tot[tid] = run;
    }
    __syncthreads();
    if (tid == 0) {
        int r = 0;
        for (int c = 0; c < NBC; ++c) { bo[c] = r; r += tot[c]; }
        boff[NBC] = r;
        off[n] = E;
    }
    __syncthreads();
    if (tid < NBC) boff[tid] = bo[tid];
    for (int i = tid; i < tote; i += 256) hist[i] = mat[i] + bo[i % NBC];
}

__global__ __launch_bounds__(256) void part_k(const int* __restrict__ src,
                                              const int* __restrict__ dst,
                                              const int* __restrict__ hist,
                                              uint* __restrict__ pairs, int E) {
    __shared__ int cur[NBC];
    const int blk = blockIdx.x;
    for (int i = threadIdx.x; i < NBC; i += 256) cur[i] = hist[blk * NBC + i];
    __syncthreads();
    const int base = blk * EPB, end = min(base + EPB, E);
    for (int e = base + threadIdx.x; e < end; e += 256) {
        int d = dst[e], s = src[e];
        int slot = atomicAdd(&cur[d >> 9], 1);
        pairs[slot] = ((uint)s << 9) | (uint)(d & 511);
    }
}

__global__ __launch_bounds__(256) void bucket_k(const uint* __restrict__ pairs,
                                                const int* __restrict__ boff,
                                                int* __restrict__ off,
                                                float* __restrict__ dinv,
                                                int* __restrict__ csr, int n) {
    __shared__ int lh[512], lcur[512], tsum[256];
    __shared__ int sorted[P4CAP];
    const int tid = threadIdx.x;
    const int cb = blockIdx.x;
    const int b0 = boff[cb], b1 = boff[cb + 1];
    const int cnt = b1 - b0;
    lh[tid] = 0; lh[tid + 256] = 0;
    __syncthreads();
    for (int i = tid; i < cnt; i += 256) atomicAdd(&lh[pairs[b0 + i] & 511], 1);
    __syncthreads();
    const int s0 = lh[2 * tid], s1 = lh[2 * tid + 1];
    const int s = s0 + s1;
    tsum[tid] = s;
    __syncthreads();
    for (int o = 1; o < 256; o <<= 1) {
        int t = (tid >= o) ? tsum[tid - o] : 0;
        __syncthreads();
        tsum[tid] += t;
        __syncthreads();
    }
    const int ex = tsum[tid] - s;
    lcur[2 * tid] = ex; lcur[2 * tid + 1] = ex + s0;
    {
        int node = cb * 512 + 2 * tid;
        if (node < n)     { off[node]     = b0 + ex;      dinv[node]     = rsqrtf((float)s0 + 1.f); }
        if (node + 1 < n) { off[node + 1] = b0 + ex + s0; dinv[node + 1] = rsqrtf((float)s1 + 1.f); }
    }
    __syncthreads();
    for (int i = tid; i < cnt; i += 256) {
        uint v = pairs[b0 + i];
        int slot = atomicAdd(&lcur[v & 511], 1);
        if (slot < P4CAP) sorted[slot] = (int)(v >> 9);
    }
    __syncthreads();
    const int cs = min(cnt, P4CAP);
    for (int i = tid; i < cs; i += 256) csr[b0 + i] = sorted[i];
}

__global__ void wt_cvt2(const float* __restrict__ W1, ushort* __restrict__ W1t,
                        const float* __restrict__ W2, ushort* __restrict__ W2t) {
    int idx = blockIdx.x * 256 + threadIdx.x;
    if (idx < DI * DH) {
        int m = idx / DI, k = idx % DI;
        W1t[idx] = f2b(W1[(long)k * DH + m]);
    }
    if (idx < DH * DO) {
        int m = idx / DH, k = idx % DH;
        W2t[idx] = f2b(W2[(long)k * DO + m]);
    }
}

// ---------------- MFMA GEMM (layer 1) ----------------
template<int K, int M, bool INF32>
__global__ __launch_bounds__(256) void mfma_gemm(const void* __restrict__ Xv,
                                                 const ushort* __restrict__ Wt,
                                                 const float* __restrict__ dinv,
                                                 ushort* __restrict__ Y, int n) {
    constexpr int ROWB = K * 2;
    constexpr int CT = M / 64;
    __shared__ ushort Xs[64 * K];
    const int t = threadIdx.x;
    const int r0 = blockIdx.x * 64;

    {
        const int row = t >> 2, q = t & 3;
        const int gr = r0 + row;
        if (INF32) {
            const float* Xr = (const float*)Xv + (long)gr * K;
#pragma unroll
            for (int j = 0; j < K / 32; ++j) {
                float4 a = make_float4(0.f, 0.f, 0.f, 0.f), b = a;
                if (gr < n) {
                    a = *(const float4*)&Xr[q * 8 + j * 32];
                    b = *(const float4*)&Xr[q * 8 + j * 32 + 4];
                }
                ushort u[8] = {f2b(a.x), f2b(a.y), f2b(a.z), f2b(a.w),
                               f2b(b.x), f2b(b.y), f2b(b.z), f2b(b.w)};
                int byte = row * ROWB + q * 16 + j * 64;
                byte ^= (row & 7) << 4;
                *(uint4*)((char*)Xs + byte) = *(const uint4*)u;
            }
        } else {
            const ushort* Xr = (const ushort*)Xv + (long)gr * K;
#pragma unroll
            for (int j = 0; j < K / 32; ++j) {
                uint4 v = make_uint4(0u, 0u, 0u, 0u);
                if (gr < n) v = *(const uint4*)&Xr[q * 8 + j * 32];
                int byte = row * ROWB + q * 16 + j * 64;
                byte ^= (row & 7) << 4;
                *(uint4*)((char*)Xs + byte) = v;
            }
        }
    }
    __syncthreads();

    const int w  = t >> 6;
    const int l  = t & 63;
    const int lr = l & 15;
    const int lg = l >> 4;
    f32x4 acc[4][CT] = {};

#pragma unroll
    for (int ks = 0; ks < K / 32; ++ks) {
        bf16x8 bfr[CT];
#pragma unroll
        for (int ct = 0; ct < CT; ++ct) {
            int col = w * (M / 4) + ct * 16 + lr;
            bfr[ct] = *(const bf16x8*)&Wt[(long)col * K + ks * 32 + lg * 8];
        }
        bf16x8 afr[4];
#pragma unroll
        for (int rt = 0; rt < 4; ++rt) {
            int row = rt * 16 + lr;
            int byte = row * ROWB + ks * 64 + lg * 16;
            byte ^= (row & 7) << 4;
            afr[rt] = *(const bf16x8*)((const char*)Xs + byte);
        }
#pragma unroll
        for (int rt = 0; rt < 4; ++rt)
#pragma unroll
            for (int ct = 0; ct < CT; ++ct)
                acc[rt][ct] = __builtin_amdgcn_mfma_f32_16x16x32_bf16(
                    afr[rt], bfr[ct], acc[rt][ct], 0, 0, 0);
    }

#pragma unroll
    for (int rt = 0; rt < 4; ++rt)
#pragma unroll
        for (int i = 0; i < 4; ++i) {
            int gr2 = r0 + rt * 16 + lg * 4 + i;
            if (gr2 < n) {
                float dv = dinv[gr2];
#pragma unroll
                for (int ct = 0; ct < CT; ++ct) {
                    int col = w * (M / 4) + ct * 16 + lr;
                    Y[(long)gr2 * M + col] = f2b(dv * acc[rt][ct][i]);
                }
            }
        }
}

// ---------------- fused: gather(h0s)+relu+bias -> LDS h -> h@W2 -> h1s ----
// 1024 threads = 16 waves. Gather: wave wv handles rows wv*4..wv*4+3 (GR=4
// edge-groups x 16 lanes, 2-edge unroll). MFMA: wave wv -> 16x16 tile
// (rt=wv>>2, ct=wv&3) of the 64x64 output.
__global__ __launch_bounds__(1024, 8) void gather_gemm(const int* __restrict__ off,
                                                       const int* __restrict__ csr,
                                                       const ushort* __restrict__ Hs,
                                                       const float* __restrict__ dinv,
                                                       const float* __restrict__ b1,
                                                       const ushort* __restrict__ W2t,
                                                       ushort* __restrict__ h1s, int n) {
    __shared__ ushort Xs[64 * DH];     // 16 KB, swizzled rows of 256B
    const int tid = threadIdx.x;
    const int wv = tid >> 6, ln = tid & 63;
    const int grp = ln >> 4, j = ln & 15;
    const int base = blockIdx.x * 64;
    const uint4* H4 = (const uint4*)Hs;

#pragma unroll
    for (int q = 0; q < 4; ++q) {
        const int row = wv * 4 + q;
        const int node = base + row;
        float a0[8] = {}, a1[8] = {};
        if (node < n) {
            const int k0 = off[node], ke = off[node + 1];
            int k = k0 + grp;
            for (; k + 4 < ke; k += 8) {
                uint4 va = H4[(long)csr[k] * 16 + j];
                uint4 vb = H4[(long)csr[k + 4] * 16 + j];
                a0[0] += blo(va.x); a0[1] += bhi(va.x);
                a0[2] += blo(va.y); a0[3] += bhi(va.y);
                a0[4] += blo(va.z); a0[5] += bhi(va.z);
                a0[6] += blo(va.w); a0[7] += bhi(va.w);
                a1[0] += blo(vb.x); a1[1] += bhi(vb.x);
                a1[2] += blo(vb.y); a1[3] += bhi(vb.y);
                a1[4] += blo(vb.z); a1[5] += bhi(vb.z);
                a1[6] += blo(vb.w); a1[7] += bhi(vb.w);
            }
            if (k < ke) {
                uint4 va = H4[(long)csr[k] * 16 + j];
                a0[0] += blo(va.x); a0[1] += bhi(va.x);
                a0[2] += blo(va.y); a0[3] += bhi(va.y);
                a0[4] += blo(va.z); a0[5] += bhi(va.z);
                a0[6] += blo(va.w); a0[7] += bhi(va.w);
            }
            if (grp == 0) {            // self loop
                uint4 va = H4[(long)node * 16 + j];
                a1[0] += blo(va.x); a1[1] += bhi(va.x);
                a1[2] += blo(va.y); a1[3] += bhi(va.y);
                a1[4] += blo(va.z); a1[5] += bhi(va.z);
                a1[6] += blo(va.w); a1[7] += bhi(va.w);
            }
        }
        float r[8];
#pragma unroll
        for (int m = 0; m < 8; ++m) {
            r[m] = a0[m] + a1[m];
            r[m] += __shfl_xor(r[m], 16, 64);
            r[m] += __shfl_xor(r[m], 32, 64);
        }
        if (grp == 0 && node < n) {
            float di = dinv[node];
            float4 bb0 = ((const float4*)b1)[j * 2];
            float4 bb1 = ((const float4*)b1)[j * 2 + 1];
            ushort u[8];
            u[0] = f2b(fmaxf(di * r[0] + bb0.x, 0.f));
            u[1] = f2b(fmaxf(di * r[1] + bb0.y, 0.f));
            u[2] = f2b(fmaxf(di * r[2] + bb0.z, 0.f));
            u[3] = f2b(fmaxf(di * r[3] + bb0.w, 0.f));
            u[4] = f2b(fmaxf(di * r[4] + bb1.x, 0.f));
            u[5] = f2b(fmaxf(di * r[5] + bb1.y, 0.f));
            u[6] = f2b(fmaxf(di * r[6] + bb1.z, 0.f));
            u[7] = f2b(fmaxf(di * r[7] + bb1.w, 0.f));
            int byte = row * 256 + j * 16;
            byte ^= (row & 7) << 4;
            *(uint4*)((char*)Xs + byte) = *(const uint4*)u;
        }
    }
    __syncthreads();

    // MFMA: 64x64 = 16 tiles of 16x16, one per wave; K=128 in 4 slices
    const int rt = wv >> 2, ct = wv & 3;
    const int lr = ln & 15, lg = ln >> 4;
    f32x4 acc = {};
#pragma unroll
    for (int ks = 0; ks < 4; ++ks) {
        bf16x8 bfr = *(const bf16x8*)&W2t[(ct * 16 + lr) * DH + ks * 32 + lg * 8];
        int rowA = rt * 16 + lr;
        int byte = rowA * 256 + ks * 64 + lg * 16;
        byte ^= (rowA & 7) << 4;
        bf16x8 afr = *(const bf16x8*)((const char*)Xs + byte);
        acc = __builtin_amdgcn_mfma_f32_16x16x32_bf16(afr, bfr, acc, 0, 0, 0);
    }
#pragma unroll
    for (int i = 0; i < 4; ++i) {
        int r2 = base + rt * 16 + lg * 4 + i;
        if (r2 < n) h1s[(long)r2 * DO + ct * 16 + lr] = f2b(dinv[r2] * acc[i]);
    }
}

// ---------------- gather layer 2: one wave per node, 2-edge unroll ----------
template<int M, bool RELU, bool OUTF32>
__global__ __launch_bounds__(256) void gather_wave(const int* __restrict__ off,
                                                   const int* __restrict__ csr,
                                                   const ushort* __restrict__ Hs,
                                                   const float* __restrict__ dinv,
                                                   const float* __restrict__ b,
                                                   void* __restrict__ Yv, int n) {
    constexpr int LPG = M / 8;         // 8 lanes per edge-group
    constexpr int GR  = 64 / LPG;      // 8 edge groups
    const int wv = threadIdx.x >> 6;
    const int ln = threadIdx.x & 63;
    const int grp = ln / LPG;
    const int j   = ln % LPG;
    const int i = blockIdx.x * 4 + wv;
    if (i >= n) return;
    const uint4* H4 = (const uint4*)Hs;
    float a0[8] = {}, a1[8] = {};
    const int k0 = off[i], ke = off[i + 1];
    int k = k0 + grp;
    for (; k + GR < ke; k += 2 * GR) {
        uint4 va = H4[(long)csr[k] * LPG + j];
        uint4 vb = H4[(long)csr[k + GR] * LPG + j];
        a0[0] += blo(va.x); a0[1] += bhi(va.x);
        a0[2] += blo(va.y); a0[3] += bhi(va.y);
        a0[4] += blo(va.z); a0[5] += bhi(va.z);
        a0[6] += blo(va.w); a0[7] += bhi(va.w);
        a1[0] += blo(vb.x); a1[1] += bhi(vb.x);
        a1[2] += blo(vb.y); a1[3] += bhi(vb.y);
        a1[4] += blo(vb.z); a1[5] += bhi(vb.z);
        a1[6] += blo(vb.w); a1[7] += bhi(vb.w);
    }
    if (k < ke) {
        uint4 va = H4[(long)csr[k] * LPG + j];
        a0[0] += blo(va.x); a0[1] += bhi(va.x);
        a0[2] += blo(va.y); a0[3] += bhi(va.y);
        a0[4] += blo(va.z); a0[5] += bhi(va.z);
        a0[6] += blo(va.w); a0[7] += bhi(va.w);
    }
    if (grp == 0) {                    // self loop
        uint4 va = H4[(long)i * LPG + j];
        a1[0] += blo(va.x); a1[1] += bhi(va.x);
        a1[2] += blo(va.y); a1[3] += bhi(va.y);
        a1[4] += blo(va.z); a1[5] += bhi(va.z);
        a1[6] += blo(va.w); a1[7] += bhi(va.w);
    }
    float acc[8];
#pragma unroll
    for (int m = 0; m < 8; ++m) {
        acc[m] = a0[m] + a1[m];
#pragma unroll
        for (int o = LPG; o < 64; o <<= 1) acc[m] += __shfl_xor(acc[m], o, 64);
    }
    if (grp == 0) {
        float di = dinv[i];
        float4 b0 = ((const float4*)b)[j * 2];
        float4 b1 = ((const float4*)b)[j * 2 + 1];
        float r[8];
        r[0] = di * acc[0] + b0.x; r[1] = di * acc[1] + b0.y;
        r[2] = di * acc[2] + b0.z; r[3] = di * acc[3] + b0.w;
        r[4] = di * acc[4] + b1.x; r[5] = di * acc[5] + b1.y;
        r[6] = di * acc[6] + b1.z; r[7] = di * acc[7] + b1.w;
        if (RELU) {
#pragma unroll
            for (int m = 0; m < 8; ++m) r[m] = fmaxf(r[m], 0.f);
        }
        if (OUTF32) {
            float* Y = (float*)Yv;
            *(float4*)&Y[(long)i * M + j * 8]     = make_float4(r[0], r[1], r[2], r[3]);
            *(float4*)&Y[(long)i * M + j * 8 + 4] = make_float4(r[4], r[5], r[6], r[7]);
        } else {
            ushort* Y = (ushort*)Yv;
            uint4 o;
            o.x = (uint)f2b(r[0]) | ((uint)f2b(r[1]) << 16);
            o.y = (uint)f2b(r[2]) | ((uint)f2b(r[3]) << 16);
            o.z = (uint)f2b(r[4]) | ((uint)f2b(r[5]) << 16);
            o.w = (uint)f2b(r[6]) | ((uint)f2b(r[7]) << 16);
            *(uint4*)&Y[(long)i * M + j * 8] = o;
        }
    }
}

extern "C" void kernel_launch(void* const* d_in, const int* in_sizes, int n_in,
                              void* d_out, int out_size, void* d_ws, size_t ws_size,
                              hipStream_t stream) {
    const float* x  = (const float*)d_in[0];
    const int*   ei = (const int*)d_in[1];
    const float* W1 = (const float*)d_in[2];
    const float* b1 = (const float*)d_in[3];
    const float* W2 = (const float*)d_in[4];
    const float* b2 = (const float*)d_in[5];
    float* out = (float*)d_out;

    const int n = in_sizes[0] / DI;   // 50000
    const int E = in_sizes[1] / 2;    // 800000
    const int* src = ei;
    const int* dst = ei + E;
    const int np  = ((n + 255) / 256) * 256;
    const int nbp = (E + EPB - 1) / EPB;   // 98
    const int nbc = (n + 511) >> 9;        // 98

    int*    hist  = (int*)d_ws;
    int*    boff  = hist + NBC * NBC;
    int*    off   = boff + 128;
    float*  dinv  = (float*)(off + np + 256);
    int*    csr   = (int*)(dinv + np);
    uint*   pairs = (uint*)(csr + E);
    ushort* w1t   = (ushort*)(pairs + E);
    ushort* w2t   = w1t + DH * DI;
    ushort* h0s   = w2t + DO * DH;
    ushort* h1s   = h0s + (size_t)n * DH;   // disjoint from h0s (fused RW)

    hist_k<<<nbp, 256, 0, stream>>>(dst, hist, E);
    scan_mat<<<1, 256, 0, stream>>>(hist, boff, off, nbp, n, E);
    part_k<<<nbp, 256, 0, stream>>>(src, dst, hist, pairs, E);
    bucket_k<<<nbc, 256, 0, stream>>>(pairs, boff, off, dinv, csr, n);
    wt_cvt2<<<(DI * DH + 255) / 256, 256, 0, stream>>>(W1, w1t, W2, w2t);

    const int gblk = (n + 63) / 64;
    mfma_gemm<DI, DH, true><<<gblk, 256, 0, stream>>>(x, w1t, dinv, h0s, n);
    gather_gemm<<<gblk, 1024, 0, stream>>>(off, csr, h0s, dinv, b1, w2t, h1s, n);
    gather_wave<DO, false, true><<<(n + 3) / 4, 256, 0, stream>>>(off, csr, h1s, dinv, b2, out, n);
}